// Round 4
// baseline (286.355 us; speedup 1.0000x reference)
//
#include <hip/hip_runtime.h>

typedef __bf16 bf16x8 __attribute__((ext_vector_type(8)));
typedef float f32x4 __attribute__((ext_vector_type(4)));
typedef unsigned short ushort8 __attribute__((ext_vector_type(8)));

#define C_DIM 512
#define N_DIM 4096
#define NBATCH 16

// ---------- helpers ----------

__device__ __forceinline__ unsigned short f2bf(float f) {
  unsigned int u = __builtin_bit_cast(unsigned int, f);
  u += 0x7FFFu + ((u >> 16) & 1u);
  return (unsigned short)(u >> 16);
}

__device__ __forceinline__ void gload_lds16(const void* g, void* l) {
  __builtin_amdgcn_global_load_lds(
      (const __attribute__((address_space(1))) void*)g,
      (__attribute__((address_space(3))) void*)l, 16, 0, 0);
}

// ---------- 1) cast + transpose: x (fp32) -> q (bf16 row-major) + qT (bf16 col-major)
// grid: 16 b * 8 c-tiles * 64 n-tiles = 8192 blocks, 256 threads. Tile 64c x 64n.
// LDS: [64 n][32 dw] with 4-dword-chunk XOR swizzle (chunk ^= n&7): dword i2 of
// row n holds (bf16 x[c0+2*i2][n], bf16 x[c0+2*i2+1][n]) packed lo|hi.

__global__ __launch_bounds__(256) void cast_transpose(
    const float* __restrict__ x, unsigned short* __restrict__ q,
    unsigned short* __restrict__ qT) {
  int bidx = blockIdx.x;
  int nt = bidx & 63;
  int ct = (bidx >> 6) & 7;
  int b  = bidx >> 9;
  int n0 = nt * 64, c0 = ct * 64;

  const float* xb = x + (size_t)b * C_DIM * N_DIM;
  unsigned short* qb = q + (size_t)b * C_DIM * N_DIM;
  unsigned short* qTb = qT + (size_t)b * N_DIM * C_DIM;

  __shared__ __align__(16) unsigned int Ls[64 * 32];

  int t = threadIdx.x;
  int j = t & 63;        // n within tile
  int i2b = t >> 6;      // c-pair sub-index

#pragma unroll
  for (int p = 0; p < 8; ++p) {
    int i2 = p * 4 + i2b;           // c-pair index 0..31
    int row0 = c0 + 2 * i2;
    float f0 = xb[(size_t)row0 * N_DIM + n0 + j];
    float f1 = xb[(size_t)(row0 + 1) * N_DIM + n0 + j];
    unsigned short b0 = f2bf(f0), b1 = f2bf(f1);
    qb[(size_t)row0 * N_DIM + n0 + j] = b0;
    qb[(size_t)(row0 + 1) * N_DIM + n0 + j] = b1;
    unsigned int val = (unsigned int)b0 | ((unsigned int)b1 << 16);
    Ls[j * 32 + (((i2 >> 2) ^ (j & 7)) * 4) + (i2 & 3)] = val;
  }
  __syncthreads();

  // write qT: thread t -> local n-row = t>>2, c-range (t&3)*16 .. +16
  int n = t >> 2;
  int a = t & 3;
  const uint4* Lsv = reinterpret_cast<const uint4*>(Ls);
  uint4 v0 = Lsv[(n * 32 + ((a * 2) ^ (n & 7)) * 4) >> 2];
  uint4 v1 = Lsv[(n * 32 + ((a * 2 + 1) ^ (n & 7)) * 4) >> 2];
  unsigned short* dst = qTb + (size_t)(n0 + n) * C_DIM + c0 + a * 16;
  reinterpret_cast<uint4*>(dst)[0] = v0;
  reinterpret_cast<uint4*>(dst)[1] = v1;
}

// ---------- 2) energy[b] += q[b] @ q[b]^T  (symmetric: upper-triangle tiles only)
// grid: 16 b * 10 tile-pairs * 4 ksplit = 640 blocks, 256 threads.
// LDS [128][64] ushort 16B-chunk XOR swizzle (linear gload_lds dest +
// pre-swizzled source + swizzled read).

__device__ __constant__ int TR_LUT[10] = {0,0,0,0,1,1,1,2,2,3};
__device__ __constant__ int TC_LUT[10] = {0,1,2,3,1,2,3,2,3,3};

__global__ __launch_bounds__(256) void gemm_qqt(
    const unsigned short* __restrict__ q, float* __restrict__ energy) {
  const int K = N_DIM;
  int bidx = blockIdx.x;
  int ks = bidx & 3;
  int p  = (bidx >> 2) % 10;
  int b  = bidx / 40;
  int tr = TR_LUT[p], tc = TC_LUT[p];
  const unsigned short* Abase = q + (size_t)(b * C_DIM + tr * 128) * K;
  const unsigned short* Bbase = q + (size_t)(b * C_DIM + tc * 128) * K;
  float* Cp = energy + (size_t)b * C_DIM * C_DIM;

  __shared__ __align__(16) unsigned short As[128 * 64];
  __shared__ __align__(16) unsigned short Bs[128 * 64];

  int t = threadIdx.x;
  int lane = t & 63;
  int w = t >> 6;
  int wr = w >> 1, wc = w & 1;

  f32x4 acc[4][4] = {};

  int k0beg = ks * (K / 4);
  for (int k0 = k0beg; k0 < k0beg + K / 4; k0 += 64) {
#pragma unroll
    for (int i = 0; i < 4; ++i) {
      int c = i * 256 + t;
      int row = c >> 3, jp = c & 7;
      int scol = ((jp ^ (row & 7)) * 8);
      gload_lds16(Abase + (size_t)row * K + k0 + scol, As + c * 8);
      gload_lds16(Bbase + (size_t)row * K + k0 + scol, Bs + c * 8);
    }
    __syncthreads();
#pragma unroll
    for (int kk = 0; kk < 2; ++kk) {
      bf16x8 af[4], bfr[4];
#pragma unroll
      for (int mi = 0; mi < 4; ++mi) {
        int row = wr * 64 + mi * 16 + (lane & 15);
        int ch = (kk * 4 + (lane >> 4)) ^ (row & 7);
        af[mi] = *reinterpret_cast<const bf16x8*>(As + row * 64 + ch * 8);
      }
#pragma unroll
      for (int ni = 0; ni < 4; ++ni) {
        int row = wc * 64 + ni * 16 + (lane & 15);
        int ch = (kk * 4 + (lane >> 4)) ^ (row & 7);
        bfr[ni] = *reinterpret_cast<const bf16x8*>(Bs + row * 64 + ch * 8);
      }
#pragma unroll
      for (int mi = 0; mi < 4; ++mi)
#pragma unroll
        for (int ni = 0; ni < 4; ++ni)
          acc[mi][ni] = __builtin_amdgcn_mfma_f32_16x16x32_bf16(
              af[mi], bfr[ni], acc[mi][ni], 0, 0, 0);
    }
    __syncthreads();
  }

  int r0 = tr * 128 + wr * 64;
  int c0 = tc * 128 + wc * 64;
  bool offdiag = (tr != tc);
#pragma unroll
  for (int mi = 0; mi < 4; ++mi)
#pragma unroll
    for (int ni = 0; ni < 4; ++ni)
#pragma unroll
      for (int r = 0; r < 4; ++r) {
        int row = r0 + mi * 16 + (lane >> 4) * 4 + r;
        int col = c0 + ni * 16 + (lane & 15);
        float v = acc[mi][ni][r];
        atomicAdd(&Cp[(size_t)row * C_DIM + col], v);
        if (offdiag) atomicAdd(&Cp[(size_t)col * C_DIM + row], v);
      }
}

// ---------- 3) att = softmax(min_row(e) - e) rowwise, write bf16 ----------

__global__ __launch_bounds__(256) void softmax_rows(
    const float* __restrict__ energy, unsigned short* __restrict__ att) {
  int w = threadIdx.x >> 6;
  int lane = threadIdx.x & 63;
  int row = blockIdx.x * 4 + w;
  const float* e = energy + (size_t)row * C_DIM;
  unsigned short* a = att + (size_t)row * C_DIM;
  float v[8];
  float mn = 3.0e38f;
#pragma unroll
  for (int j = 0; j < 8; ++j) {
    v[j] = e[j * 64 + lane];
    mn = fminf(mn, v[j]);
  }
#pragma unroll
  for (int s = 32; s >= 1; s >>= 1) mn = fminf(mn, __shfl_xor(mn, s));
  float p[8];
  float sum = 0.f;
#pragma unroll
  for (int j = 0; j < 8; ++j) {
    p[j] = __expf(mn - v[j]);
    sum += p[j];
  }
#pragma unroll
  for (int s = 32; s >= 1; s >>= 1) sum += __shfl_xor(sum, s);
  float inv = 1.0f / sum;
#pragma unroll
  for (int j = 0; j < 8; ++j) a[j * 64 + lane] = f2bf(p[j] * inv);
}

// ---------- 4a) out = gamma * (att @ q) + x, using qT  (pure NT GEMM) ----------
// A = att rows (k=c contig), B = qT rows (k=c contig). Both staged via
// swizzled global_load_lds. No transposes in the hot loop.

__global__ __launch_bounds__(256) void gemm_av(
    const unsigned short* __restrict__ att, const unsigned short* __restrict__ qT,
    const float* __restrict__ x, const float* __restrict__ gamma,
    float* __restrict__ out) {
  int bidx = blockIdx.x;
  int b  = bidx >> 7;
  int tr = (bidx >> 5) & 3;
  int tc = bidx & 31;

  const unsigned short* Abase = att + (size_t)(b * C_DIM + tr * 128) * C_DIM;
  const unsigned short* Bbase = qT + (size_t)(b * N_DIM + tc * 128) * C_DIM;

  __shared__ __align__(16) unsigned short As[128 * 64];
  __shared__ __align__(16) unsigned short Bs[128 * 64];

  int t = threadIdx.x;
  int lane = t & 63;
  int w = t >> 6;
  int wr = w >> 1, wc = w & 1;

  f32x4 acc[4][4] = {};

  for (int k0 = 0; k0 < C_DIM; k0 += 64) {
#pragma unroll
    for (int i = 0; i < 4; ++i) {
      int c = i * 256 + t;
      int row = c >> 3, jp = c & 7;
      int scol = ((jp ^ (row & 7)) * 8);
      gload_lds16(Abase + (size_t)row * C_DIM + k0 + scol, As + c * 8);
      gload_lds16(Bbase + (size_t)row * C_DIM + k0 + scol, Bs + c * 8);
    }
    __syncthreads();
#pragma unroll
    for (int kk = 0; kk < 2; ++kk) {
      bf16x8 af[4], bfr[4];
#pragma unroll
      for (int mi = 0; mi < 4; ++mi) {
        int row = wr * 64 + mi * 16 + (lane & 15);
        int ch = (kk * 4 + (lane >> 4)) ^ (row & 7);
        af[mi] = *reinterpret_cast<const bf16x8*>(As + row * 64 + ch * 8);
      }
#pragma unroll
      for (int ni = 0; ni < 4; ++ni) {
        int row = wc * 64 + ni * 16 + (lane & 15);
        int ch = (kk * 4 + (lane >> 4)) ^ (row & 7);
        bfr[ni] = *reinterpret_cast<const bf16x8*>(Bs + row * 64 + ch * 8);
      }
#pragma unroll
      for (int mi = 0; mi < 4; ++mi)
#pragma unroll
        for (int ni = 0; ni < 4; ++ni)
          acc[mi][ni] = __builtin_amdgcn_mfma_f32_16x16x32_bf16(
              af[mi], bfr[ni], acc[mi][ni], 0, 0, 0);
    }
    __syncthreads();
  }

  float g = gamma[0];
  const float* xb = x + (size_t)b * C_DIM * N_DIM;
  float* ob = out + (size_t)b * C_DIM * N_DIM;
  int r0 = tr * 128 + wr * 64;
  int n0 = tc * 128 + wc * 64;
#pragma unroll
  for (int mi = 0; mi < 4; ++mi)
#pragma unroll
    for (int ni = 0; ni < 4; ++ni)
#pragma unroll
      for (int r = 0; r < 4; ++r) {
        int row = r0 + mi * 16 + (lane >> 4) * 4 + r;
        int col = n0 + ni * 16 + (lane & 15);
        size_t idx = (size_t)row * N_DIM + col;
        ob[idx] = fmaf(g, acc[mi][ni][r], xb[idx]);
      }
}

// ---------- 4b) fallback gemm_av (no qT): reg-transpose B, coalesced loads ----------

__global__ __launch_bounds__(256) void gemm_av_fb(
    const unsigned short* __restrict__ att, const unsigned short* __restrict__ q,
    const float* __restrict__ x, const float* __restrict__ gamma,
    float* __restrict__ out) {
  int bidx = blockIdx.x;
  int b  = bidx >> 7;
  int tr = (bidx >> 5) & 3;
  int tc = bidx & 31;

  const unsigned short* Abase = att + (size_t)(b * C_DIM + tr * 128) * C_DIM;
  const unsigned short* qb = q + (size_t)b * C_DIM * N_DIM;

  __shared__ __align__(16) unsigned short As[128 * 64];
  __shared__ __align__(16) unsigned short Bs[128][72];

  int t = threadIdx.x;
  int lane = t & 63;
  int w = t >> 6;
  int wr = w >> 1, wc = w & 1;

  f32x4 acc[4][4] = {};

  for (int k0 = 0; k0 < C_DIM; k0 += 64) {
#pragma unroll
    for (int i = 0; i < 4; ++i) {
      int c = i * 256 + t;
      int row = c >> 3, jp = c & 7;
      int scol = ((jp ^ (row & 7)) * 8);
      gload_lds16(Abase + (size_t)row * C_DIM + k0 + scol, As + c * 8);
    }
    // coalesced B: consecutive lanes -> consecutive n within one q row
#pragma unroll
    for (int i = 0; i < 2; ++i) {
      int u = i * 256 + t;
      int oct = u & 15;
      int dp = u >> 4;     // 0..31
      int d = dp * 2;
      int n = oct * 8;
      const unsigned short* src = qb + (size_t)(k0 + d) * N_DIM + tc * 128 + n;
      ushort8 rA = *reinterpret_cast<const ushort8*>(src);
      ushort8 rB = *reinterpret_cast<const ushort8*>(src + N_DIM);
#pragma unroll
      for (int m = 0; m < 8; ++m) {
        unsigned int val = (unsigned int)rA[m] | ((unsigned int)rB[m] << 16);
        *reinterpret_cast<unsigned int*>(&Bs[n + m][d]) = val;
      }
    }
    __syncthreads();
#pragma unroll
    for (int kk = 0; kk < 2; ++kk) {
      bf16x8 af[4], bfr[4];
#pragma unroll
      for (int mi = 0; mi < 4; ++mi) {
        int row = wr * 64 + mi * 16 + (lane & 15);
        int ch = (kk * 4 + (lane >> 4)) ^ (row & 7);
        af[mi] = *reinterpret_cast<const bf16x8*>(As + row * 64 + ch * 8);
      }
#pragma unroll
      for (int ni = 0; ni < 4; ++ni)
        bfr[ni] = *reinterpret_cast<const bf16x8*>(
            &Bs[wc * 64 + ni * 16 + (lane & 15)][kk * 32 + (lane >> 4) * 8]);
#pragma unroll
      for (int mi = 0; mi < 4; ++mi)
#pragma unroll
        for (int ni = 0; ni < 4; ++ni)
          acc[mi][ni] = __builtin_amdgcn_mfma_f32_16x16x32_bf16(
              af[mi], bfr[ni], acc[mi][ni], 0, 0, 0);
    }
    __syncthreads();
  }

  float g = gamma[0];
  const float* xb = x + (size_t)b * C_DIM * N_DIM;
  float* ob = out + (size_t)b * C_DIM * N_DIM;
  int r0 = tr * 128 + wr * 64;
  int n0 = tc * 128 + wc * 64;
#pragma unroll
  for (int mi = 0; mi < 4; ++mi)
#pragma unroll
    for (int ni = 0; ni < 4; ++ni)
#pragma unroll
      for (int r = 0; r < 4; ++r) {
        int row = r0 + mi * 16 + (lane >> 4) * 4 + r;
        int col = n0 + ni * 16 + (lane & 15);
        size_t idx = (size_t)row * N_DIM + col;
        ob[idx] = fmaf(g, acc[mi][ni][r], xb[idx]);
      }
}

// ---------- simple cast (fallback path) ----------

__global__ __launch_bounds__(256) void cast_kernel(
    const float* __restrict__ x, unsigned short* __restrict__ q, long n8) {
  long stride = (long)gridDim.x * blockDim.x;
  for (long i = (long)blockIdx.x * blockDim.x + threadIdx.x; i < n8; i += stride) {
    const float4* xv = reinterpret_cast<const float4*>(x) + i * 2;
    float4 a = xv[0];
    float4 b = xv[1];
    ushort8 o;
    o[0] = f2bf(a.x); o[1] = f2bf(a.y); o[2] = f2bf(a.z); o[3] = f2bf(a.w);
    o[4] = f2bf(b.x); o[5] = f2bf(b.y); o[6] = f2bf(b.z); o[7] = f2bf(b.w);
    reinterpret_cast<ushort8*>(q)[i] = o;
  }
}

// ---------- launch ----------

extern "C" void kernel_launch(void* const* d_in, const int* in_sizes, int n_in,
                              void* d_out, int out_size, void* d_ws, size_t ws_size,
                              hipStream_t stream) {
  const float* x = (const float*)d_in[0];
  const float* gamma = (const float*)d_in[1];
  float* out = (float*)d_out;
  char* ws = (char*)d_ws;

  const size_t QSZ = 67108864;     // bf16 [16][512][4096]
  const size_t ESZ = 16777216;     // f32  [16][512][512]
  const size_t need = QSZ * 2 + ESZ + 8388608;

  if (ws_size >= need) {
    unsigned short* q  = (unsigned short*)ws;
    unsigned short* qT = (unsigned short*)(ws + QSZ);
    float* energy = (float*)(ws + 2 * QSZ);
    unsigned short* att = (unsigned short*)(ws + 2 * QSZ + ESZ);

    hipMemsetAsync(energy, 0, ESZ, stream);
    cast_transpose<<<8192, 256, 0, stream>>>(x, q, qT);
    gemm_qqt<<<640, 256, 0, stream>>>(q, energy);
    softmax_rows<<<2048, 256, 0, stream>>>(energy, att);
    gemm_av<<<2048, 256, 0, stream>>>(att, qT, x, gamma, out);
  } else {
    unsigned short* q = (unsigned short*)ws;
    float* energy = (float*)(ws + QSZ);
    unsigned short* att = (unsigned short*)(ws + QSZ + ESZ);

    long n8 = (long)NBATCH * C_DIM * N_DIM / 8;
    hipMemsetAsync(energy, 0, ESZ, stream);
    cast_kernel<<<2048, 256, 0, stream>>>(x, q, n8);
    gemm_qqt<<<640, 256, 0, stream>>>(q, energy);
    softmax_rows<<<2048, 256, 0, stream>>>(energy, att);
    gemm_av_fb<<<2048, 256, 0, stream>>>(att, q, x, gamma, out);
  }
}

// Round 5
// 200.088 us; speedup vs baseline: 1.4311x; 1.4311x over previous
//
#include <hip/hip_runtime.h>

typedef __bf16 bf16x8 __attribute__((ext_vector_type(8)));
typedef float f32x4 __attribute__((ext_vector_type(4)));
typedef unsigned short ushort8 __attribute__((ext_vector_type(8)));

#define C_DIM 512
#define N_DIM 4096
#define NBATCH 16
#define PSTRIDE ((size_t)NBATCH * C_DIM * C_DIM)   // elements per energy partial

// ---------- helpers ----------

__device__ __forceinline__ unsigned short f2bf(float f) {
  unsigned int u = __builtin_bit_cast(unsigned int, f);
  u += 0x7FFFu + ((u >> 16) & 1u);
  return (unsigned short)(u >> 16);
}

__device__ __forceinline__ void gload_lds16(const void* g, void* l) {
  __builtin_amdgcn_global_load_lds(
      (const __attribute__((address_space(1))) void*)g,
      (__attribute__((address_space(3))) void*)l, 16, 0, 0);
}

// ---------- cast + transpose: x (fp32) -> q (bf16) + qT (bf16) ----------

__global__ __launch_bounds__(256) void cast_transpose(
    const float* __restrict__ x, unsigned short* __restrict__ q,
    unsigned short* __restrict__ qT) {
  int bidx = blockIdx.x;
  int nt = bidx & 63;
  int ct = (bidx >> 6) & 7;
  int b  = bidx >> 9;
  int n0 = nt * 64, c0 = ct * 64;

  const float* xb = x + (size_t)b * C_DIM * N_DIM;
  unsigned short* qb = q + (size_t)b * C_DIM * N_DIM;
  unsigned short* qTb = qT + (size_t)b * N_DIM * C_DIM;

  __shared__ __align__(16) unsigned int Ls[64 * 32];

  int t = threadIdx.x;
  int j = t & 63;
  int i2b = t >> 6;

#pragma unroll
  for (int p = 0; p < 8; ++p) {
    int i2 = p * 4 + i2b;
    int row0 = c0 + 2 * i2;
    float f0 = xb[(size_t)row0 * N_DIM + n0 + j];
    float f1 = xb[(size_t)(row0 + 1) * N_DIM + n0 + j];
    unsigned short b0 = f2bf(f0), b1 = f2bf(f1);
    qb[(size_t)row0 * N_DIM + n0 + j] = b0;
    qb[(size_t)(row0 + 1) * N_DIM + n0 + j] = b1;
    unsigned int val = (unsigned int)b0 | ((unsigned int)b1 << 16);
    Ls[j * 32 + (((i2 >> 2) ^ (j & 7)) * 4) + (i2 & 3)] = val;
  }
  __syncthreads();

  int n = t >> 2;
  int a = t & 3;
  const uint4* Lsv = reinterpret_cast<const uint4*>(Ls);
  uint4 v0 = Lsv[(n * 32 + ((a * 2) ^ (n & 7)) * 4) >> 2];
  uint4 v1 = Lsv[(n * 32 + ((a * 2 + 1) ^ (n & 7)) * 4) >> 2];
  unsigned short* dst = qTb + (size_t)(n0 + n) * C_DIM + c0 + a * 16;
  reinterpret_cast<uint4*>(dst)[0] = v0;
  reinterpret_cast<uint4*>(dst)[1] = v1;
}

// ---------- simple cast (fallback tiers) ----------

__global__ __launch_bounds__(256) void cast_kernel(
    const float* __restrict__ x, unsigned short* __restrict__ q, long n8) {
  long stride = (long)gridDim.x * blockDim.x;
  for (long i = (long)blockIdx.x * blockDim.x + threadIdx.x; i < n8; i += stride) {
    const float4* xv = reinterpret_cast<const float4*>(x) + i * 2;
    float4 a = xv[0];
    float4 b = xv[1];
    ushort8 o;
    o[0] = f2bf(a.x); o[1] = f2bf(a.y); o[2] = f2bf(a.z); o[3] = f2bf(a.w);
    o[4] = f2bf(b.x); o[5] = f2bf(b.y); o[6] = f2bf(b.z); o[7] = f2bf(b.w);
    reinterpret_cast<ushort8*>(q)[i] = o;
  }
}

// ---------- energy partials: ep[ks][b] = q[b](ks-slice) @ q[b]^T ----------
// grid = 256 << ksbits blocks; plain coalesced stores, NO atomics.
// LDS [128][64] ushort 16B-chunk XOR swizzle (linear gload_lds dest +
// pre-swizzled source + swizzled read) — measured 0 bank conflicts (r4).

__global__ __launch_bounds__(256) void gemm_qqt(
    const unsigned short* __restrict__ q, float* __restrict__ epart, int ksbits) {
  const int K = N_DIM;
  int bidx = blockIdx.x;
  int ks = bidx & ((1 << ksbits) - 1);
  int rest = bidx >> ksbits;
  int p = rest & 15;
  int b = rest >> 4;
  int tr = p >> 2, tc = p & 3;
  const unsigned short* Abase = q + (size_t)(b * C_DIM + tr * 128) * K;
  const unsigned short* Bbase = q + (size_t)(b * C_DIM + tc * 128) * K;
  float* Cp = epart + (size_t)ks * PSTRIDE + (size_t)b * C_DIM * C_DIM;

  __shared__ __align__(16) unsigned short As[128 * 64];
  __shared__ __align__(16) unsigned short Bs[128 * 64];

  int t = threadIdx.x;
  int lane = t & 63;
  int w = t >> 6;
  int wr = w >> 1, wc = w & 1;

  f32x4 acc[4][4] = {};

  int klen = K >> ksbits;
  int k0beg = ks * klen;
  for (int k0 = k0beg; k0 < k0beg + klen; k0 += 64) {
#pragma unroll
    for (int i = 0; i < 4; ++i) {
      int c = i * 256 + t;
      int row = c >> 3, jp = c & 7;
      int scol = ((jp ^ (row & 7)) * 8);
      gload_lds16(Abase + (size_t)row * K + k0 + scol, As + c * 8);
      gload_lds16(Bbase + (size_t)row * K + k0 + scol, Bs + c * 8);
    }
    __syncthreads();
#pragma unroll
    for (int kk = 0; kk < 2; ++kk) {
      bf16x8 af[4], bfr[4];
#pragma unroll
      for (int mi = 0; mi < 4; ++mi) {
        int row = wr * 64 + mi * 16 + (lane & 15);
        int ch = (kk * 4 + (lane >> 4)) ^ (row & 7);
        af[mi] = *reinterpret_cast<const bf16x8*>(As + row * 64 + ch * 8);
      }
#pragma unroll
      for (int ni = 0; ni < 4; ++ni) {
        int row = wc * 64 + ni * 16 + (lane & 15);
        int ch = (kk * 4 + (lane >> 4)) ^ (row & 7);
        bfr[ni] = *reinterpret_cast<const bf16x8*>(Bs + row * 64 + ch * 8);
      }
#pragma unroll
      for (int mi = 0; mi < 4; ++mi)
#pragma unroll
        for (int ni = 0; ni < 4; ++ni)
          acc[mi][ni] = __builtin_amdgcn_mfma_f32_16x16x32_bf16(
              af[mi], bfr[ni], acc[mi][ni], 0, 0, 0);
    }
    __syncthreads();
  }

  int r0 = tr * 128 + wr * 64;
  int c0 = tc * 128 + wc * 64;
#pragma unroll
  for (int mi = 0; mi < 4; ++mi)
#pragma unroll
    for (int ni = 0; ni < 4; ++ni)
#pragma unroll
      for (int r = 0; r < 4; ++r) {
        int row = r0 + mi * 16 + (lane >> 4) * 4 + r;
        int col = c0 + ni * 16 + (lane & 15);
        Cp[(size_t)row * C_DIM + col] = acc[mi][ni][r];
      }
}

// ---------- softmax over sum of partials ----------

__global__ __launch_bounds__(256) void softmax_rows(
    const float* __restrict__ epart, unsigned short* __restrict__ att, int ns) {
  int w = threadIdx.x >> 6;
  int lane = threadIdx.x & 63;
  int row = blockIdx.x * 4 + w;
  const float* e0 = epart + (size_t)row * C_DIM;
  unsigned short* a = att + (size_t)row * C_DIM;
  float v[8];
  float mn = 3.0e38f;
#pragma unroll
  for (int j = 0; j < 8; ++j) {
    float s = e0[j * 64 + lane];
    if (ns == 2) s += e0[PSTRIDE + j * 64 + lane];
    v[j] = s;
    mn = fminf(mn, s);
  }
#pragma unroll
  for (int s = 32; s >= 1; s >>= 1) mn = fminf(mn, __shfl_xor(mn, s));
  float p[8];
  float sum = 0.f;
#pragma unroll
  for (int j = 0; j < 8; ++j) {
    p[j] = __expf(mn - v[j]);
    sum += p[j];
  }
#pragma unroll
  for (int s = 32; s >= 1; s >>= 1) sum += __shfl_xor(sum, s);
  float inv = 1.0f / sum;
#pragma unroll
  for (int j = 0; j < 8; ++j) a[j * 64 + lane] = f2bf(p[j] * inv);
}

// ---------- out = gamma * (att @ q) + x via qT (pure NT GEMM) ----------

__global__ __launch_bounds__(256) void gemm_av(
    const unsigned short* __restrict__ att, const unsigned short* __restrict__ qT,
    const float* __restrict__ x, const float* __restrict__ gamma,
    float* __restrict__ out) {
  int bidx = blockIdx.x;
  int b  = bidx >> 7;
  int tr = (bidx >> 5) & 3;
  int tc = bidx & 31;

  const unsigned short* Abase = att + (size_t)(b * C_DIM + tr * 128) * C_DIM;
  const unsigned short* Bbase = qT + (size_t)(b * N_DIM + tc * 128) * C_DIM;

  __shared__ __align__(16) unsigned short As[128 * 64];
  __shared__ __align__(16) unsigned short Bs[128 * 64];

  int t = threadIdx.x;
  int lane = t & 63;
  int w = t >> 6;
  int wr = w >> 1, wc = w & 1;

  f32x4 acc[4][4] = {};

  for (int k0 = 0; k0 < C_DIM; k0 += 64) {
#pragma unroll
    for (int i = 0; i < 4; ++i) {
      int c = i * 256 + t;
      int row = c >> 3, jp = c & 7;
      int scol = ((jp ^ (row & 7)) * 8);
      gload_lds16(Abase + (size_t)row * C_DIM + k0 + scol, As + c * 8);
      gload_lds16(Bbase + (size_t)row * C_DIM + k0 + scol, Bs + c * 8);
    }
    __syncthreads();
#pragma unroll
    for (int kk = 0; kk < 2; ++kk) {
      bf16x8 af[4], bfr[4];
#pragma unroll
      for (int mi = 0; mi < 4; ++mi) {
        int row = wr * 64 + mi * 16 + (lane & 15);
        int ch = (kk * 4 + (lane >> 4)) ^ (row & 7);
        af[mi] = *reinterpret_cast<const bf16x8*>(As + row * 64 + ch * 8);
      }
#pragma unroll
      for (int ni = 0; ni < 4; ++ni) {
        int row = wc * 64 + ni * 16 + (lane & 15);
        int ch = (kk * 4 + (lane >> 4)) ^ (row & 7);
        bfr[ni] = *reinterpret_cast<const bf16x8*>(Bs + row * 64 + ch * 8);
      }
#pragma unroll
      for (int mi = 0; mi < 4; ++mi)
#pragma unroll
        for (int ni = 0; ni < 4; ++ni)
          acc[mi][ni] = __builtin_amdgcn_mfma_f32_16x16x32_bf16(
              af[mi], bfr[ni], acc[mi][ni], 0, 0, 0);
    }
    __syncthreads();
  }

  float g = gamma[0];
  const float* xb = x + (size_t)b * C_DIM * N_DIM;
  float* ob = out + (size_t)b * C_DIM * N_DIM;
  int r0 = tr * 128 + wr * 64;
  int n0 = tc * 128 + wc * 64;
#pragma unroll
  for (int mi = 0; mi < 4; ++mi)
#pragma unroll
    for (int ni = 0; ni < 4; ++ni)
#pragma unroll
      for (int r = 0; r < 4; ++r) {
        int row = r0 + mi * 16 + (lane >> 4) * 4 + r;
        int col = n0 + ni * 16 + (lane & 15);
        size_t idx = (size_t)row * N_DIM + col;
        ob[idx] = fmaf(g, acc[mi][ni][r], xb[idx]);
      }
}

// ---------- fallback gemm_av (no qT): reg-transpose B ----------

__global__ __launch_bounds__(256) void gemm_av_fb(
    const unsigned short* __restrict__ att, const unsigned short* __restrict__ q,
    const float* __restrict__ x, const float* __restrict__ gamma,
    float* __restrict__ out) {
  int bidx = blockIdx.x;
  int b  = bidx >> 7;
  int tr = (bidx >> 5) & 3;
  int tc = bidx & 31;

  const unsigned short* Abase = att + (size_t)(b * C_DIM + tr * 128) * C_DIM;
  const unsigned short* qb = q + (size_t)b * C_DIM * N_DIM;

  __shared__ __align__(16) unsigned short As[128 * 64];
  __shared__ __align__(16) unsigned short Bs[128][72];

  int t = threadIdx.x;
  int lane = t & 63;
  int w = t >> 6;
  int wr = w >> 1, wc = w & 1;

  f32x4 acc[4][4] = {};

  for (int k0 = 0; k0 < C_DIM; k0 += 64) {
#pragma unroll
    for (int i = 0; i < 4; ++i) {
      int c = i * 256 + t;
      int row = c >> 3, jp = c & 7;
      int scol = ((jp ^ (row & 7)) * 8);
      gload_lds16(Abase + (size_t)row * C_DIM + k0 + scol, As + c * 8);
    }
#pragma unroll
    for (int i = 0; i < 2; ++i) {
      int u = i * 256 + t;
      int oct = u & 15;
      int dp = u >> 4;
      int d = dp * 2;
      int n = oct * 8;
      const unsigned short* src = qb + (size_t)(k0 + d) * N_DIM + tc * 128 + n;
      ushort8 rA = *reinterpret_cast<const ushort8*>(src);
      ushort8 rB = *reinterpret_cast<const ushort8*>(src + N_DIM);
#pragma unroll
      for (int m = 0; m < 8; ++m) {
        unsigned int val = (unsigned int)rA[m] | ((unsigned int)rB[m] << 16);
        *reinterpret_cast<unsigned int*>(&Bs[n + m][d]) = val;
      }
    }
    __syncthreads();
#pragma unroll
    for (int kk = 0; kk < 2; ++kk) {
      bf16x8 af[4], bfr[4];
#pragma unroll
      for (int mi = 0; mi < 4; ++mi) {
        int row = wr * 64 + mi * 16 + (lane & 15);
        int ch = (kk * 4 + (lane >> 4)) ^ (row & 7);
        af[mi] = *reinterpret_cast<const bf16x8*>(As + row * 64 + ch * 8);
      }
#pragma unroll
      for (int ni = 0; ni < 4; ++ni)
        bfr[ni] = *reinterpret_cast<const bf16x8*>(
            &Bs[wc * 64 + ni * 16 + (lane & 15)][kk * 32 + (lane >> 4) * 8]);
#pragma unroll
      for (int mi = 0; mi < 4; ++mi)
#pragma unroll
        for (int ni = 0; ni < 4; ++ni)
          acc[mi][ni] = __builtin_amdgcn_mfma_f32_16x16x32_bf16(
              af[mi], bfr[ni], acc[mi][ni], 0, 0, 0);
    }
    __syncthreads();
  }

  float g = gamma[0];
  const float* xb = x + (size_t)b * C_DIM * N_DIM;
  float* ob = out + (size_t)b * C_DIM * N_DIM;
  int r0 = tr * 128 + wr * 64;
  int n0 = tc * 128 + wc * 64;
#pragma unroll
  for (int mi = 0; mi < 4; ++mi)
#pragma unroll
    for (int ni = 0; ni < 4; ++ni)
#pragma unroll
      for (int r = 0; r < 4; ++r) {
        int row = r0 + mi * 16 + (lane >> 4) * 4 + r;
        int col = n0 + ni * 16 + (lane & 15);
        size_t idx = (size_t)row * N_DIM + col;
        ob[idx] = fmaf(g, acc[mi][ni][r], xb[idx]);
      }
}

// ---------- launch ----------

extern "C" void kernel_launch(void* const* d_in, const int* in_sizes, int n_in,
                              void* d_out, int out_size, void* d_ws, size_t ws_size,
                              hipStream_t stream) {
  const float* x = (const float*)d_in[0];
  const float* gamma = (const float*)d_in[1];
  float* out = (float*)d_out;
  char* ws = (char*)d_ws;

  const size_t QSZ = 67108864;   // bf16 [16][512][4096]
  const size_t ESZ = 16777216;   // f32  [16][512][512] (one partial)
  const size_t ASZ = 8388608;    // bf16 [16][512][512]
  long n8 = (long)NBATCH * C_DIM * N_DIM / 8;

  if (ws_size >= 2 * QSZ + 2 * ESZ + ASZ) {              // 176,160,768: tier A
    unsigned short* q  = (unsigned short*)ws;
    unsigned short* qT = (unsigned short*)(ws + QSZ);
    float* ep = (float*)(ws + 2 * QSZ);
    unsigned short* att = (unsigned short*)(ws + 2 * QSZ + 2 * ESZ);
    cast_transpose<<<8192, 256, 0, stream>>>(x, q, qT);
    gemm_qqt<<<512, 256, 0, stream>>>(q, ep, 1);
    softmax_rows<<<2048, 256, 0, stream>>>(ep, att, 2);
    gemm_av<<<2048, 256, 0, stream>>>(att, qT, x, gamma, out);
  } else if (ws_size >= QSZ + 2 * ESZ + ASZ) {           // 109,051,904: tier B
    unsigned short* q = (unsigned short*)ws;
    float* ep = (float*)(ws + QSZ);
    unsigned short* att = (unsigned short*)(ws + QSZ + 2 * ESZ);
    cast_kernel<<<2048, 256, 0, stream>>>(x, q, n8);
    gemm_qqt<<<512, 256, 0, stream>>>(q, ep, 1);
    softmax_rows<<<2048, 256, 0, stream>>>(ep, att, 2);
    gemm_av_fb<<<2048, 256, 0, stream>>>(att, q, x, gamma, out);
  } else {                                               // 92,274,688: tier C
    unsigned short* q = (unsigned short*)ws;
    float* ep = (float*)(ws + QSZ);
    unsigned short* att = (unsigned short*)(ws + QSZ + ESZ);
    cast_kernel<<<2048, 256, 0, stream>>>(x, q, n8);
    gemm_qqt<<<256, 256, 0, stream>>>(q, ep, 0);
    softmax_rows<<<2048, 256, 0, stream>>>(ep, att, 1);
    gemm_av_fb<<<2048, 256, 0, stream>>>(att, q, x, gamma, out);
  }
}